// Round 9
// baseline (2108.799 us; speedup 1.0000x reference)
//
#include <hip/hip_runtime.h>
#include <math.h>

#define NATOM 4096
#define NM    1024
#define NKR   9260      // real k-vectors (21^3 - 1)
#define KSPLIT 14
#define CHPS  22        // chunks per split
#define NCH   308       // KSPLIT*CHPS
#define KC    32
#define KPAD2 9856      // NCH*KC
#define PI_F  3.14159265358979f

typedef float v4 __attribute__((ext_vector_type(4)));
static __device__ __forceinline__ v4 splat4(float x){ v4 r = {x,x,x,x}; return r; }

// ---------- k-vector data computed inline (device helper) ----------
static __device__ __forceinline__ void kdata(int t, const float* __restrict__ cell,
                                             float& kxx, float& kyy, float& kzz, float& w) {
  if (t >= NKR) { kxx = 0.f; kyy = 0.f; kzz = 0.f; w = 0.f; return; }
  int u = (t < 4630) ? t : t + 1;       // skip the all-zero triple
  int a = u / 441;
  int rem = u - a * 441;
  int b = rem / 21;
  int c = rem - b * 21;
  float na = (float)(a - 10), nb = (float)(b - 10), nc = (float)(c - 10);
  float m00=cell[0], m01=cell[1], m02=cell[2];
  float m10=cell[3], m11=cell[4], m12=cell[5];
  float m20=cell[6], m21=cell[7], m22=cell[8];
  float det = m00*(m11*m22 - m12*m21) - m01*(m10*m22 - m12*m20) + m02*(m10*m21 - m11*m20);
  float inv00 =  (m11*m22 - m12*m21) / det;
  float inv01 = -(m01*m22 - m02*m21) / det;
  float inv02 =  (m01*m12 - m02*m11) / det;
  float inv10 = -(m10*m22 - m12*m20) / det;
  float inv11 =  (m00*m22 - m02*m20) / det;
  float inv12 = -(m00*m12 - m02*m10) / det;
  float inv20 =  (m10*m21 - m11*m20) / det;
  float inv21 = -(m00*m21 - m01*m20) / det;
  float inv22 =  (m00*m11 - m01*m10) / det;
  const float twopi = 2.f * PI_F;
  kxx = twopi * (na*inv00 + nb*inv01 + nc*inv02);
  kyy = twopi * (na*inv10 + nb*inv11 + nc*inv12);
  kzz = twopi * (na*inv20 + nb*inv21 + nc*inv22);
  float k2 = kxx*kxx + kyy*kyy + kzz*kzz;
  const float sigma = 1.0f / 1.805132f;
  w = (4.f * PI_F / fabsf(det)) * __expf(-0.5f * sigma * sigma * k2) / k2;
}

// ---------- sfk: k-data + structure factors in one kernel.
__global__ __launch_bounds__(256)
void sfk(const float* __restrict__ pos, const float* __restrict__ q,
         const float* __restrict__ cell,
         float* __restrict__ kx, float* __restrict__ ky,
         float* __restrict__ kz, float* __restrict__ ksw,
         float* __restrict__ gc, float* __restrict__ gs) {
  __shared__ float red1[8][32], red2[8][32];
  const int kloc = threadIdx.x & 31;
  const int part = threadIdx.x >> 5;             // 0..7
  const int k = blockIdx.x * 32 + kloc;          // < KPAD2
  float kxx, kyy, kzz, w;
  kdata(k, cell, kxx, kyy, kzz, w);
  if (part == 0) { kx[k]=kxx; ky[k]=kyy; kz[k]=kzz; ksw[k]=sqrtf(w); }
  float sc = 0.f, ss = 0.f;
  const int j0 = NM + part * 384, j1 = j0 + 384;
  for (int j = j0; j < j1; ++j) {
    float kr = kxx*pos[3*j] + kyy*pos[3*j+1] + kzz*pos[3*j+2];
    float s, c;
    __sincosf(kr, &s, &c);
    float qj = q[j];
    sc += qj * c;
    ss += qj * s;
  }
  red1[part][kloc] = sc;
  red2[part][kloc] = ss;
  __syncthreads();
  if (part == 0) {
    float tc = 0.f, ts = 0.f;
    #pragma unroll
    for (int pp = 0; pp < 8; ++pp) { tc += red1[pp][kloc]; ts += red2[pp][kloc]; }
    gc[k] = w * tc;
    gs[k] = w * ts;
  }
}

// ----------------- B = -f at metal positions; also init r2 = ones
__global__ __launch_bounds__(256)
void fB(const float* __restrict__ pos,
        const float* __restrict__ kx, const float* __restrict__ ky,
        const float* __restrict__ kz,
        const float* __restrict__ gc, const float* __restrict__ gs,
        float* __restrict__ r1, float* __restrict__ r2) {
  int i = blockIdx.x;
  float px = pos[3*i], py = pos[3*i+1], pz = pos[3*i+2];
  float p = 0.f;
  for (int k = threadIdx.x; k < KPAD2; k += 256) {
    float kr = kx[k]*px + ky[k]*py + kz[k]*pz;
    float s, c;
    __sincosf(kr, &s, &c);
    p += gc[k]*c + gs[k]*s;
  }
  for (int o = 32; o > 0; o >>= 1) p += __shfl_down(p, o, 64);
  __shared__ float red[4];
  if ((threadIdx.x & 63) == 0) red[threadIdx.x >> 6] = p;
  __syncthreads();
  if (threadIdx.x == 0) {
    r1[i] = -(red[0] + red[1] + red[2] + red[3]);
    r2[i] = 1.f;
  }
}

// --------------- A = C W C^T + S W S^T, upper 128-tiles only (bi<=bj)
__global__ __launch_bounds__(256, 2)
void gemmA(const float* __restrict__ pos,
           const float* __restrict__ kx, const float* __restrict__ ky,
           const float* __restrict__ kz, const float* __restrict__ ksw,
           float* __restrict__ A) {
  __shared__ __align__(16) float Cr[KC][128];
  __shared__ __align__(16) float Sr[KC][128];
  __shared__ __align__(16) float Cc[KC][128];
  __shared__ __align__(16) float Sc[KC][128];
  const int blk = blockIdx.x;
  const int split = blk / 36;
  const int tt = blk - split * 36;
  int bi = 0, rem = tt;
  while (rem >= 8 - bi) { rem -= 8 - bi; ++bi; }
  const int bj = bi + rem;
  const int t = threadIdx.x;
  const int side = t >> 7;
  const int a = t & 127;
  const int atom = (side ? bj : bi) * 128 + a;
  const float px = pos[3*atom], py = pos[3*atom+1], pz = pos[3*atom+2];
  float (*Cp)[128] = side ? Cc : Cr;
  float (*Sp)[128] = side ? Sc : Sr;
  const int ri0 = (t >> 4) * 4;
  const int c0  = (t & 15) * 4;
  v4 acc[2][2][4];
  #pragma unroll
  for (int qi = 0; qi < 2; ++qi)
    #pragma unroll
    for (int qj = 0; qj < 2; ++qj)
      #pragma unroll
      for (int ii = 0; ii < 4; ++ii)
        acc[qi][qj][ii] = splat4(0.f);

  for (int ch = split * CHPS; ch < split * CHPS + CHPS; ++ch) {
    const int kb = ch * KC;
    #pragma unroll 4
    for (int kk = 0; kk < KC; ++kk) {
      const int gk = kb + kk;
      float kr = kx[gk]*px + ky[gk]*py + kz[gk]*pz;
      float s, c;
      __sincosf(kr, &s, &c);
      float sw = ksw[gk];
      Cp[kk][a] = c * sw;
      Sp[kk][a] = s * sw;
    }
    __syncthreads();
    #pragma unroll 2
    for (int kk = 0; kk < KC; ++kk) {
      v4 cr0 = *(const v4*)&Cr[kk][ri0];
      v4 cr1 = *(const v4*)&Cr[kk][ri0+64];
      v4 sr0 = *(const v4*)&Sr[kk][ri0];
      v4 sr1 = *(const v4*)&Sr[kk][ri0+64];
      v4 cc0 = *(const v4*)&Cc[kk][c0];
      v4 cc1 = *(const v4*)&Cc[kk][c0+64];
      v4 sc0 = *(const v4*)&Sc[kk][c0];
      v4 sc1 = *(const v4*)&Sc[kk][c0+64];
      #pragma unroll
      for (int ii = 0; ii < 4; ++ii) {
        acc[0][0][ii] += cc0 * splat4(cr0[ii]);
        acc[0][0][ii] += sc0 * splat4(sr0[ii]);
        acc[0][1][ii] += cc1 * splat4(cr0[ii]);
        acc[0][1][ii] += sc1 * splat4(sr0[ii]);
        acc[1][0][ii] += cc0 * splat4(cr1[ii]);
        acc[1][0][ii] += sc0 * splat4(sr1[ii]);
        acc[1][1][ii] += cc1 * splat4(cr1[ii]);
        acc[1][1][ii] += sc1 * splat4(sr1[ii]);
      }
    }
    __syncthreads();
  }
  #pragma unroll
  for (int qi = 0; qi < 2; ++qi)
    #pragma unroll
    for (int qj = 0; qj < 2; ++qj)
      #pragma unroll
      for (int ii = 0; ii < 4; ++ii) {
        const int row = bi*128 + qi*64 + ri0 + ii;
        const int col = bj*128 + qj*64 + c0;
        atomicAdd(&A[row*1024 + col + 0], acc[qi][qj][ii][0]);
        atomicAdd(&A[row*1024 + col + 1], acc[qi][qj][ii][1]);
        atomicAdd(&A[row*1024 + col + 2], acc[qi][qj][ii][2]);
        atomicAdd(&A[row*1024 + col + 3], acc[qi][qj][ii][3]);
      }
}

// ============ step(p): fused lazy-syrk + panel, one launch per p ============
// Same structure as R8; chol/TRSM rewritten as ROLLED outer loops over an
// LDS-resident tile with a colbuf pivot-column broadcast (code ~2KB instead
// of ~100KB straight-line; kills the I-fetch stall). colbuf[m]=0 for m<=j
// makes the rank-1 update unconditional (zero-update = exact no-op).
__global__ __launch_bounds__(256)
void step(float* __restrict__ A, const float* __restrict__ r1, const float* __restrict__ r2,
          float* __restrict__ ru1, float* __restrict__ ru2,
          float* __restrict__ y1g, float* __restrict__ y2g, int p) {
  __shared__ float D[64][65];
  __shared__ float T[64][65];
  __shared__ float colbuf[64];
  __shared__ float y1s[64], y2s[64];
  __shared__ float ps1[4][64], ps2[4][64];
  const int t = threadIdx.x;
  const int lane = t & 63;
  const int part = t >> 6;
  const int c0 = part * 16;
  const int nb = 16 - p;
  const int i0 = (t >> 4) * 4, j0 = (t & 15) * 4;

  if ((int)blockIdx.x >= nb) {
    // ---------------- syrk role (only launched for p >= 1) ----------------
    int rem = blockIdx.x - nb, a = 0;
    while (rem >= a + 1) { rem -= (a + 1); ++a; }
    const int qi = p + 1 + a, qj = p + 1 + rem;
    for (int e = t; e < 4096; e += 256) {
      int r = e >> 6, c = e & 63;
      D[r][c] = A[(qi*64+r)*1024 + (p-1)*64 + c];   // L(qi,p-1)
      T[r][c] = A[(qj*64+r)*1024 + (p-1)*64 + c];   // L(qj,p-1)
    }
    float o[4][4];
    // first touch at p==1: cross-128 lower tiles exist only as upper transpose
    if (p == 1 && (qi >> 1) != (qj >> 1)) {
      #pragma unroll
      for (int ii = 0; ii < 4; ++ii)
        #pragma unroll
        for (int jj = 0; jj < 4; ++jj)
          o[ii][jj] = A[(qj*64 + j0+jj)*1024 + qi*64 + i0+ii];
    } else {
      #pragma unroll
      for (int ii = 0; ii < 4; ++ii)
        #pragma unroll
        for (int jj = 0; jj < 4; ++jj)
          o[ii][jj] = A[(qi*64+i0+ii)*1024 + qj*64 + j0+jj];
    }
    __syncthreads();
    for (int m = 0; m < 64; ++m) {
      float a0 = D[i0+0][m], a1 = D[i0+1][m], a2 = D[i0+2][m], a3 = D[i0+3][m];
      float b0 = T[j0+0][m], b1 = T[j0+1][m], b2 = T[j0+2][m], b3 = T[j0+3][m];
      o[0][0]-=a0*b0; o[0][1]-=a0*b1; o[0][2]-=a0*b2; o[0][3]-=a0*b3;
      o[1][0]-=a1*b0; o[1][1]-=a1*b1; o[1][2]-=a1*b2; o[1][3]-=a1*b3;
      o[2][0]-=a2*b0; o[2][1]-=a2*b1; o[2][2]-=a2*b2; o[2][3]-=a2*b3;
      o[3][0]-=a3*b0; o[3][1]-=a3*b1; o[3][2]-=a3*b2; o[3][3]-=a3*b3;
    }
    #pragma unroll
    for (int ii = 0; ii < 4; ++ii)
      #pragma unroll
      for (int jj = 0; jj < 4; ++jj)
        A[(qi*64+i0+ii)*1024 + qj*64 + j0+jj] = o[ii][jj];
    return;
  }

  // ---------------- panel role: tile (q, p) ----------------
  const int b = blockIdx.x;
  const int q = p + b;
  if (p == 0) {
    for (int e = t; e < 4096; e += 256)
      D[e>>6][e&63] = A[(e>>6)*1024 + (e&63)];                      // A(0,0)
    if (b > 0) {
      if (q == 1) {
        for (int e = t; e < 4096; e += 256)
          T[e>>6][e&63] = A[(q*64+(e>>6))*1024 + (e&63)];           // A(1,0) direct
      } else {
        for (int e = t; e < 4096; e += 256)
          T[e&63][e>>6] = A[(e>>6)*1024 + q*64 + (e&63)];           // A(0,q)^T
      }
    }
    __syncthreads();
  } else {
    // load column p-1 L tiles
    for (int e = t; e < 4096; e += 256)
      D[e>>6][e&63] = A[(p*64+(e>>6))*1024 + (p-1)*64 + (e&63)];    // L(p,p-1)
    if (b > 0)
      for (int e = t; e < 4096; e += 256)
        T[e>>6][e&63] = A[(q*64+(e>>6))*1024 + (p-1)*64 + (e&63)];  // L(q,p-1)
    __syncthreads();
    // diag update o1 = A(p,p) - L(p,p-1) L(p,p-1)^T  (micro, regs)
    float o1[4][4];
    #pragma unroll
    for (int ii = 0; ii < 4; ++ii)
      #pragma unroll
      for (int jj = 0; jj < 4; ++jj)
        o1[ii][jj] = A[(p*64+i0+ii)*1024 + p*64 + j0+jj];
    for (int m = 0; m < 64; ++m) {
      float a0 = D[i0+0][m], a1 = D[i0+1][m], a2 = D[i0+2][m], a3 = D[i0+3][m];
      float b0 = D[j0+0][m], b1 = D[j0+1][m], b2 = D[j0+2][m], b3 = D[j0+3][m];
      o1[0][0]-=a0*b0; o1[0][1]-=a0*b1; o1[0][2]-=a0*b2; o1[0][3]-=a0*b3;
      o1[1][0]-=a1*b0; o1[1][1]-=a1*b1; o1[1][2]-=a1*b2; o1[1][3]-=a1*b3;
      o1[2][0]-=a2*b0; o1[2][1]-=a2*b1; o1[2][2]-=a2*b2; o1[2][3]-=a2*b3;
      o1[3][0]-=a3*b0; o1[3][1]-=a3*b1; o1[3][2]-=a3*b2; o1[3][3]-=a3*b3;
    }
    float o2[4][4];
    if (b > 0) {
      // own-tile update o2 = A(q,p) - L(q,p-1) L(p,p-1)^T
      if (p == 1) {
        // first touch: read A(1,q)^T (q >= 2)
        #pragma unroll
        for (int ii = 0; ii < 4; ++ii)
          #pragma unroll
          for (int jj = 0; jj < 4; ++jj)
            o2[ii][jj] = A[(1*64 + j0+jj)*1024 + q*64 + i0+ii];
      } else {
        #pragma unroll
        for (int ii = 0; ii < 4; ++ii)
          #pragma unroll
          for (int jj = 0; jj < 4; ++jj)
            o2[ii][jj] = A[(q*64+i0+ii)*1024 + p*64 + j0+jj];
      }
      for (int m = 0; m < 64; ++m) {
        float a0 = T[i0+0][m], a1 = T[i0+1][m], a2 = T[i0+2][m], a3 = T[i0+3][m];
        float b0 = D[j0+0][m], b1 = D[j0+1][m], b2 = D[j0+2][m], b3 = D[j0+3][m];
        o2[0][0]-=a0*b0; o2[0][1]-=a0*b1; o2[0][2]-=a0*b2; o2[0][3]-=a0*b3;
        o2[1][0]-=a1*b0; o2[1][1]-=a1*b1; o2[1][2]-=a1*b2; o2[1][3]-=a1*b3;
        o2[2][0]-=a2*b0; o2[2][1]-=a2*b1; o2[2][2]-=a2*b2; o2[2][3]-=a2*b3;
        o2[3][0]-=a3*b0; o2[3][1]-=a3*b1; o2[3][2]-=a3*b2; o2[3][3]-=a3*b3;
      }
    }
    __syncthreads();   // done reading D,T as L-tiles
    #pragma unroll
    for (int ii = 0; ii < 4; ++ii)
      #pragma unroll
      for (int jj = 0; jj < 4; ++jj)
        D[i0+ii][j0+jj] = o1[ii][jj];
    if (b > 0) {
      #pragma unroll
      for (int ii = 0; ii < 4; ++ii)
        #pragma unroll
        for (int jj = 0; jj < 4; ++jj)
          T[i0+ii][j0+jj] = o2[ii][jj];
    }
    __syncthreads();
  }

  // ---- ROLLED-LDS Cholesky of D (wave 0; lane = row) ----
  // colbuf[m] = L[m][j] for m>j else 0 -> unconditional rank-1 update.
  if (t < 64) {
    for (int j = 0; j < 64; ++j) {
      float djj = D[j][j];                 // broadcast
      float rinv = rsqrtf(djj);
      float lij = D[t][j] * rinv;          // own element, conflict-free
      D[t][j] = lij;
      colbuf[t] = (t <= j) ? 0.f : lij;
      #pragma unroll
      for (int m = 0; m < 64; ++m)
        D[t][m] -= lij * colbuf[m];        // colbuf[j]=0 preserves L column
    }
  }
  __syncthreads();
  if (b == 0) {
    for (int e = t; e < 4096; e += 256) {
      int i = e >> 6, j = e & 63;
      if (i >= j) A[(p*64+i)*1024 + p*64 + j] = D[i][j];
    }
  } else {
    // ---- ROLLED-LDS TRSM: solve X L^T = T (right-looking, lane = row) ----
    if (t < 64) {
      for (int jj = 0; jj < 64; ++jj) {
        float djj = D[jj][jj];             // broadcast
        float xjj = T[t][jj] / djj;
        T[t][jj] = xjj;
        colbuf[t] = (t <= jj) ? 0.f : D[t][jj];
        #pragma unroll
        for (int m = 0; m < 64; ++m)
          T[t][m] -= xjj * colbuf[m];      // colbuf[jj]=0 preserves x column
      }
    }
    __syncthreads();
    for (int e = t; e < 4096; e += 256)
      A[(q*64 + (e>>6))*1024 + p*64 + (e&63)] = T[e>>6][e&63];
  }
  __syncthreads();
  // forward solve y_p = L_pp^{-1} r_p (redundant per block, wave 0; rolled)
  if (t < 64) {
    float v1 = r1[p*64 + t], v2 = r2[p*64 + t];
    for (int j = 0; j < 64; ++j) {
      float invd = 1.f / D[j][j];
      float Lij = D[t][j];
      float x1 = __shfl(v1, j) * invd;
      float x2 = __shfl(v2, j) * invd;
      if (t == j)      { v1 = x1; v2 = x2; }
      else if (t > j)  { v1 -= Lij * x1; v2 -= Lij * x2; }
    }
    y1s[t] = v1; y2s[t] = v2;
    if (b == 0) { y1g[p*64 + t] = v1; y2g[p*64 + t] = v2; }
  }
  __syncthreads();
  if (b > 0) {
    float a1 = 0.f, a2 = 0.f;
    for (int j = c0; j < c0 + 16; ++j) {
      float lv = T[lane][j];
      a1 += lv * y1s[j];
      a2 += lv * y2s[j];
    }
    ps1[part][lane] = a1; ps2[part][lane] = a2;
    __syncthreads();
    if (t < 64) {
      ru1[q*64 + t] -= ps1[0][t] + ps1[1][t] + ps1[2][t] + ps1[3][t];
      ru2[q*64 + t] -= ps2[0][t] + ps2[1][t] + ps2[2][t] + ps2[3][t];
    }
  }
}

// --------- backward solve (L^T x = y, 2 RHS), lambda, final output
__global__ __launch_bounds__(1024)
void bwd_out(const float* __restrict__ A, float* __restrict__ y1g, float* __restrict__ y2g,
             const float* __restrict__ qin, float* __restrict__ out) {
  __shared__ float D[64][65];
  __shared__ float x1s[64], x2s[64];
  __shared__ float rs1[16], rs2[16];
  const int t = threadIdx.x;
  for (int p = 15; p >= 0; --p) {
    for (int e = t; e < 4096; e += 1024)
      D[e>>6][e&63] = A[(p*64 + (e>>6))*1024 + p*64 + (e&63)];
    __syncthreads();
    if (t < 64) {
      float v1 = y1g[p*64 + t], v2 = y2g[p*64 + t];
      for (int i = 63; i >= 0; --i) {
        float invd = 1.f / D[i][i];
        float x1 = __shfl(v1, i) * invd;
        float x2 = __shfl(v2, i) * invd;
        float Lim = D[i][t];
        if (t == i)      { v1 = x1; v2 = x2; }
        else if (t < i)  { v1 -= Lim * x1; v2 -= Lim * x2; }
      }
      y1g[p*64 + t] = v1; y2g[p*64 + t] = v2;
      x1s[t] = v1; x2s[t] = v2;
    }
    __syncthreads();
    for (int rr = t; rr < p*64; rr += 1024) {
      float a1 = 0.f, a2 = 0.f;
      #pragma unroll 8
      for (int jj = 0; jj < 64; ++jj) {
        float lv = A[(p*64+jj)*1024 + rr];
        a1 += lv * x1s[jj];
        a2 += lv * x2s[jj];
      }
      y1g[rr] -= a1; y2g[rr] -= a2;
    }
    __syncthreads();
  }
  float s1 = y1g[t], s2 = y2g[t];
  for (int o = 32; o > 0; o >>= 1) { s1 += __shfl_down(s1, o, 64); s2 += __shfl_down(s2, o, 64); }
  if ((t & 63) == 0) { rs1[t >> 6] = s1; rs2[t >> 6] = s2; }
  __syncthreads();
  if (t == 0) {
    float a = 0.f, bb = 0.f;
    #pragma unroll
    for (int w = 0; w < 16; ++w) { a += rs1[w]; bb += rs2[w]; }
    rs1[0] = a / bb;
  }
  __syncthreads();
  const float lam = rs1[0];
  out[t] = y1g[t] - lam * y2g[t];
  for (int e = NM + t; e < NATOM; e += 1024) out[e] = qin[e];
}

// --------------------------------------------------------------- launch
extern "C" void kernel_launch(void* const* d_in, const int* in_sizes, int n_in,
                              void* d_out, int out_size, void* d_ws, size_t ws_size,
                              hipStream_t stream) {
  const float* pos  = (const float*)d_in[0];
  const float* q    = (const float*)d_in[1];
  const float* cell = (const float*)d_in[2];
  float* out = (float*)d_out;

  float* ws  = (float*)d_ws;
  float* A   = ws;                                   // 1,048,576 floats
  float* kx  = ws + 1048576;
  float* ky  = kx + KPAD2;
  float* kz  = ky + KPAD2;
  float* ksw = kz + KPAD2;
  float* gc  = ksw + KPAD2;                          // KPAD2
  float* gs  = gc + KPAD2;                           // KPAD2
  float* r1  = gs + KPAD2;                           // 1024
  float* r2  = r1 + 1024;                            // 1024
  float* y1g = r2 + 1024;                            // 1024
  float* y2g = y1g + 1024;                           // 1024

  sfk<<<NCH, 256, 0, stream>>>(pos, q, cell, kx, ky, kz, ksw, gc, gs);
  fB<<<NM, 256, 0, stream>>>(pos, kx, ky, kz, gc, gs, r1, r2);
  hipMemsetAsync(A, 0, 1024 * 1024 * sizeof(float), stream);
  gemmA<<<36 * KSPLIT, 256, 0, stream>>>(pos, kx, ky, kz, ksw, A);
  for (int p = 0; p < 16; ++p) {
    const int s = 15 - p;
    const int grid = (16 - p) + ((p >= 1) ? s * (s + 1) / 2 : 0);
    step<<<grid, 256, 0, stream>>>(A, r1, r2, r1, r2, y1g, y2g, p);
  }
  bwd_out<<<1, 1024, 0, stream>>>(A, y1g, y2g, q, out);
}

// Round 10
// 1528.062 us; speedup vs baseline: 1.3800x; 1.3800x over previous
//
#include <hip/hip_runtime.h>
#include <math.h>

#define NATOM 4096
#define NM    1024
#define NKR   9260      // real k-vectors (21^3 - 1)
#define KSPLIT 14
#define CHPS  22        // chunks per split
#define NCH   308       // KSPLIT*CHPS
#define KC    32
#define KPAD2 9856      // NCH*KC
#define PI_F  3.14159265358979f

typedef float v4 __attribute__((ext_vector_type(4)));
static __device__ __forceinline__ v4 splat4(float x){ v4 r = {x,x,x,x}; return r; }

// ---------- k-vector data computed inline (device helper) ----------
static __device__ __forceinline__ void kdata(int t, const float* __restrict__ cell,
                                             float& kxx, float& kyy, float& kzz, float& w) {
  if (t >= NKR) { kxx = 0.f; kyy = 0.f; kzz = 0.f; w = 0.f; return; }
  int u = (t < 4630) ? t : t + 1;       // skip the all-zero triple
  int a = u / 441;
  int rem = u - a * 441;
  int b = rem / 21;
  int c = rem - b * 21;
  float na = (float)(a - 10), nb = (float)(b - 10), nc = (float)(c - 10);
  float m00=cell[0], m01=cell[1], m02=cell[2];
  float m10=cell[3], m11=cell[4], m12=cell[5];
  float m20=cell[6], m21=cell[7], m22=cell[8];
  float det = m00*(m11*m22 - m12*m21) - m01*(m10*m22 - m12*m20) + m02*(m10*m21 - m11*m20);
  float inv00 =  (m11*m22 - m12*m21) / det;
  float inv01 = -(m01*m22 - m02*m21) / det;
  float inv02 =  (m01*m12 - m02*m11) / det;
  float inv10 = -(m10*m22 - m12*m20) / det;
  float inv11 =  (m00*m22 - m02*m20) / det;
  float inv12 = -(m00*m12 - m02*m10) / det;
  float inv20 =  (m10*m21 - m11*m20) / det;
  float inv21 = -(m00*m21 - m01*m20) / det;
  float inv22 =  (m00*m11 - m01*m10) / det;
  const float twopi = 2.f * PI_F;
  kxx = twopi * (na*inv00 + nb*inv01 + nc*inv02);
  kyy = twopi * (na*inv10 + nb*inv11 + nc*inv12);
  kzz = twopi * (na*inv20 + nb*inv21 + nc*inv22);
  float k2 = kxx*kxx + kyy*kyy + kzz*kzz;
  const float sigma = 1.0f / 1.805132f;
  w = (4.f * PI_F / fabsf(det)) * __expf(-0.5f * sigma * sigma * k2) / k2;
}

// ---------- sfk: k-data + structure factors in one kernel.
__global__ __launch_bounds__(256)
void sfk(const float* __restrict__ pos, const float* __restrict__ q,
         const float* __restrict__ cell,
         float* __restrict__ kx, float* __restrict__ ky,
         float* __restrict__ kz, float* __restrict__ ksw,
         float* __restrict__ gc, float* __restrict__ gs) {
  __shared__ float red1[8][32], red2[8][32];
  const int kloc = threadIdx.x & 31;
  const int part = threadIdx.x >> 5;             // 0..7
  const int k = blockIdx.x * 32 + kloc;          // < KPAD2
  float kxx, kyy, kzz, w;
  kdata(k, cell, kxx, kyy, kzz, w);
  if (part == 0) { kx[k]=kxx; ky[k]=kyy; kz[k]=kzz; ksw[k]=sqrtf(w); }
  float sc = 0.f, ss = 0.f;
  const int j0 = NM + part * 384, j1 = j0 + 384;
  for (int j = j0; j < j1; ++j) {
    float kr = kxx*pos[3*j] + kyy*pos[3*j+1] + kzz*pos[3*j+2];
    float s, c;
    __sincosf(kr, &s, &c);
    float qj = q[j];
    sc += qj * c;
    ss += qj * s;
  }
  red1[part][kloc] = sc;
  red2[part][kloc] = ss;
  __syncthreads();
  if (part == 0) {
    float tc = 0.f, ts = 0.f;
    #pragma unroll
    for (int pp = 0; pp < 8; ++pp) { tc += red1[pp][kloc]; ts += red2[pp][kloc]; }
    gc[k] = w * tc;
    gs[k] = w * ts;
  }
}

// ----------------- B = -f at metal positions; also init r2 = ones
__global__ __launch_bounds__(256)
void fB(const float* __restrict__ pos,
        const float* __restrict__ kx, const float* __restrict__ ky,
        const float* __restrict__ kz,
        const float* __restrict__ gc, const float* __restrict__ gs,
        float* __restrict__ r1, float* __restrict__ r2) {
  int i = blockIdx.x;
  float px = pos[3*i], py = pos[3*i+1], pz = pos[3*i+2];
  float p = 0.f;
  for (int k = threadIdx.x; k < KPAD2; k += 256) {
    float kr = kx[k]*px + ky[k]*py + kz[k]*pz;
    float s, c;
    __sincosf(kr, &s, &c);
    p += gc[k]*c + gs[k]*s;
  }
  for (int o = 32; o > 0; o >>= 1) p += __shfl_down(p, o, 64);
  __shared__ float red[4];
  if ((threadIdx.x & 63) == 0) red[threadIdx.x >> 6] = p;
  __syncthreads();
  if (threadIdx.x == 0) {
    r1[i] = -(red[0] + red[1] + red[2] + red[3]);
    r2[i] = 1.f;
  }
}

// --------------- A = C W C^T + S W S^T, upper 128-tiles only (bi<=bj)
__global__ __launch_bounds__(256, 2)
void gemmA(const float* __restrict__ pos,
           const float* __restrict__ kx, const float* __restrict__ ky,
           const float* __restrict__ kz, const float* __restrict__ ksw,
           float* __restrict__ A) {
  __shared__ __align__(16) float Cr[KC][128];
  __shared__ __align__(16) float Sr[KC][128];
  __shared__ __align__(16) float Cc[KC][128];
  __shared__ __align__(16) float Sc[KC][128];
  const int blk = blockIdx.x;
  const int split = blk / 36;
  const int tt = blk - split * 36;
  int bi = 0, rem = tt;
  while (rem >= 8 - bi) { rem -= 8 - bi; ++bi; }
  const int bj = bi + rem;
  const int t = threadIdx.x;
  const int side = t >> 7;
  const int a = t & 127;
  const int atom = (side ? bj : bi) * 128 + a;
  const float px = pos[3*atom], py = pos[3*atom+1], pz = pos[3*atom+2];
  float (*Cp)[128] = side ? Cc : Cr;
  float (*Sp)[128] = side ? Sc : Sr;
  const int ri0 = (t >> 4) * 4;
  const int c0  = (t & 15) * 4;
  v4 acc[2][2][4];
  #pragma unroll
  for (int qi = 0; qi < 2; ++qi)
    #pragma unroll
    for (int qj = 0; qj < 2; ++qj)
      #pragma unroll
      for (int ii = 0; ii < 4; ++ii)
        acc[qi][qj][ii] = splat4(0.f);

  for (int ch = split * CHPS; ch < split * CHPS + CHPS; ++ch) {
    const int kb = ch * KC;
    #pragma unroll 4
    for (int kk = 0; kk < KC; ++kk) {
      const int gk = kb + kk;
      float kr = kx[gk]*px + ky[gk]*py + kz[gk]*pz;
      float s, c;
      __sincosf(kr, &s, &c);
      float sw = ksw[gk];
      Cp[kk][a] = c * sw;
      Sp[kk][a] = s * sw;
    }
    __syncthreads();
    #pragma unroll 2
    for (int kk = 0; kk < KC; ++kk) {
      v4 cr0 = *(const v4*)&Cr[kk][ri0];
      v4 cr1 = *(const v4*)&Cr[kk][ri0+64];
      v4 sr0 = *(const v4*)&Sr[kk][ri0];
      v4 sr1 = *(const v4*)&Sr[kk][ri0+64];
      v4 cc0 = *(const v4*)&Cc[kk][c0];
      v4 cc1 = *(const v4*)&Cc[kk][c0+64];
      v4 sc0 = *(const v4*)&Sc[kk][c0];
      v4 sc1 = *(const v4*)&Sc[kk][c0+64];
      #pragma unroll
      for (int ii = 0; ii < 4; ++ii) {
        acc[0][0][ii] += cc0 * splat4(cr0[ii]);
        acc[0][0][ii] += sc0 * splat4(sr0[ii]);
        acc[0][1][ii] += cc1 * splat4(cr0[ii]);
        acc[0][1][ii] += sc1 * splat4(sr0[ii]);
        acc[1][0][ii] += cc0 * splat4(cr1[ii]);
        acc[1][0][ii] += sc0 * splat4(sr1[ii]);
        acc[1][1][ii] += cc1 * splat4(cr1[ii]);
        acc[1][1][ii] += sc1 * splat4(sr1[ii]);
      }
    }
    __syncthreads();
  }
  #pragma unroll
  for (int qi = 0; qi < 2; ++qi)
    #pragma unroll
    for (int qj = 0; qj < 2; ++qj)
      #pragma unroll
      for (int ii = 0; ii < 4; ++ii) {
        const int row = bi*128 + qi*64 + ri0 + ii;
        const int col = bj*128 + qj*64 + c0;
        atomicAdd(&A[row*1024 + col + 0], acc[qi][qj][ii][0]);
        atomicAdd(&A[row*1024 + col + 1], acc[qi][qj][ii][1]);
        atomicAdd(&A[row*1024 + col + 2], acc[qi][qj][ii][2]);
        atomicAdd(&A[row*1024 + col + 3], acc[qi][qj][ii][3]);
      }
}

// ============ step(p): fused lazy-syrk + panel, one launch per p ============
// R8 structure; TRSM rewritten as BLOCKED-REGISTER (16 cols/block, 4 blocks):
// live regs ~16 (no spill), previously-solved cols re-read from own LDS row
// (2-way bank alias = free), L read as same-address broadcasts. Chol keeps
// R8's wave-register form (a[64] only live array at that point).
__global__ __launch_bounds__(256)
void step(float* __restrict__ A, const float* __restrict__ r1, const float* __restrict__ r2,
          float* __restrict__ ru1, float* __restrict__ ru2,
          float* __restrict__ y1g, float* __restrict__ y2g, int p) {
  __shared__ float D[64][65];
  __shared__ float T[64][65];
  __shared__ float y1s[64], y2s[64];
  __shared__ float ps1[4][64], ps2[4][64];
  const int t = threadIdx.x;
  const int lane = t & 63;
  const int part = t >> 6;
  const int c0 = part * 16;
  const int nb = 16 - p;
  const int i0 = (t >> 4) * 4, j0 = (t & 15) * 4;

  if ((int)blockIdx.x >= nb) {
    // ---------------- syrk role (only launched for p >= 1) ----------------
    int rem = blockIdx.x - nb, a = 0;
    while (rem >= a + 1) { rem -= (a + 1); ++a; }
    const int qi = p + 1 + a, qj = p + 1 + rem;
    for (int e = t; e < 4096; e += 256) {
      int r = e >> 6, c = e & 63;
      D[r][c] = A[(qi*64+r)*1024 + (p-1)*64 + c];   // L(qi,p-1)
      T[r][c] = A[(qj*64+r)*1024 + (p-1)*64 + c];   // L(qj,p-1)
    }
    float o[4][4];
    // first touch at p==1: cross-128 lower tiles exist only as upper transpose
    if (p == 1 && (qi >> 1) != (qj >> 1)) {
      #pragma unroll
      for (int ii = 0; ii < 4; ++ii)
        #pragma unroll
        for (int jj = 0; jj < 4; ++jj)
          o[ii][jj] = A[(qj*64 + j0+jj)*1024 + qi*64 + i0+ii];
    } else {
      #pragma unroll
      for (int ii = 0; ii < 4; ++ii)
        #pragma unroll
        for (int jj = 0; jj < 4; ++jj)
          o[ii][jj] = A[(qi*64+i0+ii)*1024 + qj*64 + j0+jj];
    }
    __syncthreads();
    for (int m = 0; m < 64; ++m) {
      float a0 = D[i0+0][m], a1 = D[i0+1][m], a2 = D[i0+2][m], a3 = D[i0+3][m];
      float b0 = T[j0+0][m], b1 = T[j0+1][m], b2 = T[j0+2][m], b3 = T[j0+3][m];
      o[0][0]-=a0*b0; o[0][1]-=a0*b1; o[0][2]-=a0*b2; o[0][3]-=a0*b3;
      o[1][0]-=a1*b0; o[1][1]-=a1*b1; o[1][2]-=a1*b2; o[1][3]-=a1*b3;
      o[2][0]-=a2*b0; o[2][1]-=a2*b1; o[2][2]-=a2*b2; o[2][3]-=a2*b3;
      o[3][0]-=a3*b0; o[3][1]-=a3*b1; o[3][2]-=a3*b2; o[3][3]-=a3*b3;
    }
    #pragma unroll
    for (int ii = 0; ii < 4; ++ii)
      #pragma unroll
      for (int jj = 0; jj < 4; ++jj)
        A[(qi*64+i0+ii)*1024 + qj*64 + j0+jj] = o[ii][jj];
    return;
  }

  // ---------------- panel role: tile (q, p) ----------------
  const int b = blockIdx.x;
  const int q = p + b;
  if (p == 0) {
    for (int e = t; e < 4096; e += 256)
      D[e>>6][e&63] = A[(e>>6)*1024 + (e&63)];                      // A(0,0)
    if (b > 0) {
      if (q == 1) {
        for (int e = t; e < 4096; e += 256)
          T[e>>6][e&63] = A[(q*64+(e>>6))*1024 + (e&63)];           // A(1,0) direct
      } else {
        for (int e = t; e < 4096; e += 256)
          T[e&63][e>>6] = A[(e>>6)*1024 + q*64 + (e&63)];           // A(0,q)^T
      }
    }
    __syncthreads();
  } else {
    // load column p-1 L tiles
    for (int e = t; e < 4096; e += 256)
      D[e>>6][e&63] = A[(p*64+(e>>6))*1024 + (p-1)*64 + (e&63)];    // L(p,p-1)
    if (b > 0)
      for (int e = t; e < 4096; e += 256)
        T[e>>6][e&63] = A[(q*64+(e>>6))*1024 + (p-1)*64 + (e&63)];  // L(q,p-1)
    __syncthreads();
    // diag update o1 = A(p,p) - L(p,p-1) L(p,p-1)^T  (micro, regs)
    float o1[4][4];
    #pragma unroll
    for (int ii = 0; ii < 4; ++ii)
      #pragma unroll
      for (int jj = 0; jj < 4; ++jj)
        o1[ii][jj] = A[(p*64+i0+ii)*1024 + p*64 + j0+jj];
    for (int m = 0; m < 64; ++m) {
      float a0 = D[i0+0][m], a1 = D[i0+1][m], a2 = D[i0+2][m], a3 = D[i0+3][m];
      float b0 = D[j0+0][m], b1 = D[j0+1][m], b2 = D[j0+2][m], b3 = D[j0+3][m];
      o1[0][0]-=a0*b0; o1[0][1]-=a0*b1; o1[0][2]-=a0*b2; o1[0][3]-=a0*b3;
      o1[1][0]-=a1*b0; o1[1][1]-=a1*b1; o1[1][2]-=a1*b2; o1[1][3]-=a1*b3;
      o1[2][0]-=a2*b0; o1[2][1]-=a2*b1; o1[2][2]-=a2*b2; o1[2][3]-=a2*b3;
      o1[3][0]-=a3*b0; o1[3][1]-=a3*b1; o1[3][2]-=a3*b2; o1[3][3]-=a3*b3;
    }
    float o2[4][4];
    if (b > 0) {
      // own-tile update o2 = A(q,p) - L(q,p-1) L(p,p-1)^T
      if (p == 1) {
        // first touch: read A(1,q)^T (q >= 2)
        #pragma unroll
        for (int ii = 0; ii < 4; ++ii)
          #pragma unroll
          for (int jj = 0; jj < 4; ++jj)
            o2[ii][jj] = A[(1*64 + j0+jj)*1024 + q*64 + i0+ii];
      } else {
        #pragma unroll
        for (int ii = 0; ii < 4; ++ii)
          #pragma unroll
          for (int jj = 0; jj < 4; ++jj)
            o2[ii][jj] = A[(q*64+i0+ii)*1024 + p*64 + j0+jj];
      }
      for (int m = 0; m < 64; ++m) {
        float a0 = T[i0+0][m], a1 = T[i0+1][m], a2 = T[i0+2][m], a3 = T[i0+3][m];
        float b0 = D[j0+0][m], b1 = D[j0+1][m], b2 = D[j0+2][m], b3 = D[j0+3][m];
        o2[0][0]-=a0*b0; o2[0][1]-=a0*b1; o2[0][2]-=a0*b2; o2[0][3]-=a0*b3;
        o2[1][0]-=a1*b0; o2[1][1]-=a1*b1; o2[1][2]-=a1*b2; o2[1][3]-=a1*b3;
        o2[2][0]-=a2*b0; o2[2][1]-=a2*b1; o2[2][2]-=a2*b2; o2[2][3]-=a2*b3;
        o2[3][0]-=a3*b0; o2[3][1]-=a3*b1; o2[3][2]-=a3*b2; o2[3][3]-=a3*b3;
      }
    }
    __syncthreads();   // done reading D,T as L-tiles
    #pragma unroll
    for (int ii = 0; ii < 4; ++ii)
      #pragma unroll
      for (int jj = 0; jj < 4; ++jj)
        D[i0+ii][j0+jj] = o1[ii][jj];
    if (b > 0) {
      #pragma unroll
      for (int ii = 0; ii < 4; ++ii)
        #pragma unroll
        for (int jj = 0; jj < 4; ++jj)
          T[i0+ii][j0+jj] = o2[ii][jj];
    }
    __syncthreads();
  }

  // ---- wave-register Cholesky of D (wave 0; lane = row) — R8 verbatim ----
  if (t < 64) {
    float a[64];
    #pragma unroll
    for (int m = 0; m < 64; ++m) a[m] = D[t][m];
    #pragma unroll
    for (int j = 0; j < 64; ++j) {
      float dj = __shfl(a[j], j);
      float rinv = rsqrtf(dj);
      float lj = (t == j) ? dj * rinv : a[j] * rinv;
      a[j] = lj;
      #pragma unroll
      for (int m = j + 1; m < 64; ++m)
        a[m] -= lj * __shfl(lj, m);
    }
    #pragma unroll
    for (int m = 0; m < 64; ++m) D[t][m] = a[m];  // upper garbage, never read
  }
  __syncthreads();
  if (b == 0) {
    for (int e = t; e < 4096; e += 256) {
      int i = e >> 6, j = e & 63;
      if (i >= j) A[(p*64+i)*1024 + p*64 + j] = D[i][j];
    }
  } else {
    // ---- BLOCKED-REGISTER TRSM: solve X L^T = T (wave 0; lane = row) ----
    // x chunk of 16 regs; solved cols re-read from own LDS row; L broadcast.
    if (t < 64) {
      #pragma unroll
      for (int cb = 0; cb < 4; ++cb) {
        const int cbase = cb * 16;
        float x[16];
        #pragma unroll
        for (int k = 0; k < 16; ++k) x[k] = T[t][cbase + k];
        for (int m = 0; m < cbase; ++m) {
          float tm = T[t][m];                       // own solved value
          #pragma unroll
          for (int k = 0; k < 16; ++k)
            x[k] -= tm * D[cbase + k][m];           // broadcast L read
        }
        #pragma unroll
        for (int k = 0; k < 16; ++k) {
          float xv = x[k] * (1.0f / D[cbase + k][cbase + k]);
          x[k] = xv;
          #pragma unroll
          for (int m2 = k + 1; m2 < 16; ++m2)
            x[m2] -= xv * D[cbase + m2][cbase + k];
        }
        #pragma unroll
        for (int k = 0; k < 16; ++k) T[t][cbase + k] = x[k];
      }
    }
    __syncthreads();
    for (int e = t; e < 4096; e += 256)
      A[(q*64 + (e>>6))*1024 + p*64 + (e&63)] = T[e>>6][e&63];
  }
  __syncthreads();
  // forward solve y_p = L_pp^{-1} r_p (redundant per block, wave 0)
  if (t < 64) {
    float v1 = r1[p*64 + t], v2 = r2[p*64 + t];
    for (int j = 0; j < 64; ++j) {
      float invd = 1.f / D[j][j];
      float Lij = D[t][j];
      float x1 = __shfl(v1, j) * invd;
      float x2 = __shfl(v2, j) * invd;
      if (t == j)      { v1 = x1; v2 = x2; }
      else if (t > j)  { v1 -= Lij * x1; v2 -= Lij * x2; }
    }
    y1s[t] = v1; y2s[t] = v2;
    if (b == 0) { y1g[p*64 + t] = v1; y2g[p*64 + t] = v2; }
  }
  __syncthreads();
  if (b > 0) {
    float a1 = 0.f, a2 = 0.f;
    for (int j = c0; j < c0 + 16; ++j) {
      float lv = T[lane][j];
      a1 += lv * y1s[j];
      a2 += lv * y2s[j];
    }
    ps1[part][lane] = a1; ps2[part][lane] = a2;
    __syncthreads();
    if (t < 64) {
      ru1[q*64 + t] -= ps1[0][t] + ps1[1][t] + ps1[2][t] + ps1[3][t];
      ru2[q*64 + t] -= ps2[0][t] + ps2[1][t] + ps2[2][t] + ps2[3][t];
    }
  }
}

// --------- backward solve (L^T x = y, 2 RHS), lambda, final output
__global__ __launch_bounds__(1024)
void bwd_out(const float* __restrict__ A, float* __restrict__ y1g, float* __restrict__ y2g,
             const float* __restrict__ qin, float* __restrict__ out) {
  __shared__ float D[64][65];
  __shared__ float x1s[64], x2s[64];
  __shared__ float rs1[16], rs2[16];
  const int t = threadIdx.x;
  for (int p = 15; p >= 0; --p) {
    for (int e = t; e < 4096; e += 1024)
      D[e>>6][e&63] = A[(p*64 + (e>>6))*1024 + p*64 + (e&63)];
    __syncthreads();
    if (t < 64) {
      float v1 = y1g[p*64 + t], v2 = y2g[p*64 + t];
      for (int i = 63; i >= 0; --i) {
        float invd = 1.f / D[i][i];
        float x1 = __shfl(v1, i) * invd;
        float x2 = __shfl(v2, i) * invd;
        float Lim = D[i][t];
        if (t == i)      { v1 = x1; v2 = x2; }
        else if (t < i)  { v1 -= Lim * x1; v2 -= Lim * x2; }
      }
      y1g[p*64 + t] = v1; y2g[p*64 + t] = v2;
      x1s[t] = v1; x2s[t] = v2;
    }
    __syncthreads();
    for (int rr = t; rr < p*64; rr += 1024) {
      float a1 = 0.f, a2 = 0.f;
      #pragma unroll 8
      for (int jj = 0; jj < 64; ++jj) {
        float lv = A[(p*64+jj)*1024 + rr];
        a1 += lv * x1s[jj];
        a2 += lv * x2s[jj];
      }
      y1g[rr] -= a1; y2g[rr] -= a2;
    }
    __syncthreads();
  }
  float s1 = y1g[t], s2 = y2g[t];
  for (int o = 32; o > 0; o >>= 1) { s1 += __shfl_down(s1, o, 64); s2 += __shfl_down(s2, o, 64); }
  if ((t & 63) == 0) { rs1[t >> 6] = s1; rs2[t >> 6] = s2; }
  __syncthreads();
  if (t == 0) {
    float a = 0.f, bb = 0.f;
    #pragma unroll
    for (int w = 0; w < 16; ++w) { a += rs1[w]; bb += rs2[w]; }
    rs1[0] = a / bb;
  }
  __syncthreads();
  const float lam = rs1[0];
  out[t] = y1g[t] - lam * y2g[t];
  for (int e = NM + t; e < NATOM; e += 1024) out[e] = qin[e];
}

// --------------------------------------------------------------- launch
extern "C" void kernel_launch(void* const* d_in, const int* in_sizes, int n_in,
                              void* d_out, int out_size, void* d_ws, size_t ws_size,
                              hipStream_t stream) {
  const float* pos  = (const float*)d_in[0];
  const float* q    = (const float*)d_in[1];
  const float* cell = (const float*)d_in[2];
  float* out = (float*)d_out;

  float* ws  = (float*)d_ws;
  float* A   = ws;                                   // 1,048,576 floats
  float* kx  = ws + 1048576;
  float* ky  = kx + KPAD2;
  float* kz  = ky + KPAD2;
  float* ksw = kz + KPAD2;
  float* gc  = ksw + KPAD2;                          // KPAD2
  float* gs  = gc + KPAD2;                           // KPAD2
  float* r1  = gs + KPAD2;                           // 1024
  float* r2  = r1 + 1024;                            // 1024
  float* y1g = r2 + 1024;                            // 1024
  float* y2g = y1g + 1024;                           // 1024

  sfk<<<NCH, 256, 0, stream>>>(pos, q, cell, kx, ky, kz, ksw, gc, gs);
  fB<<<NM, 256, 0, stream>>>(pos, kx, ky, kz, gc, gs, r1, r2);
  hipMemsetAsync(A, 0, 1024 * 1024 * sizeof(float), stream);
  gemmA<<<36 * KSPLIT, 256, 0, stream>>>(pos, kx, ky, kz, ksw, A);
  for (int p = 0; p < 16; ++p) {
    const int s = 15 - p;
    const int grid = (16 - p) + ((p >= 1) ? s * (s + 1) / 2 : 0);
    step<<<grid, 256, 0, stream>>>(A, r1, r2, r1, r2, y1g, y2g, p);
  }
  bwd_out<<<1, 1024, 0, stream>>>(A, y1g, y2g, q, out);
}

// Round 11
// 1181.974 us; speedup vs baseline: 1.7841x; 1.2928x over previous
//
#include <hip/hip_runtime.h>
#include <math.h>

#define NATOM 4096
#define NM    1024
#define NKR   9260      // real k-vectors (21^3 - 1)
#define KSPLIT 14
#define CHPS  22        // chunks per split
#define NCH   308       // KSPLIT*CHPS
#define KC    32
#define KPAD2 9856      // NCH*KC
#define PI_F  3.14159265358979f

typedef float v4 __attribute__((ext_vector_type(4)));
static __device__ __forceinline__ v4 splat4(float x){ v4 r = {x,x,x,x}; return r; }

// ---------- k-vector data computed inline (device helper) ----------
static __device__ __forceinline__ void kdata(int t, const float* __restrict__ cell,
                                             float& kxx, float& kyy, float& kzz, float& w) {
  if (t >= NKR) { kxx = 0.f; kyy = 0.f; kzz = 0.f; w = 0.f; return; }
  int u = (t < 4630) ? t : t + 1;       // skip the all-zero triple
  int a = u / 441;
  int rem = u - a * 441;
  int b = rem / 21;
  int c = rem - b * 21;
  float na = (float)(a - 10), nb = (float)(b - 10), nc = (float)(c - 10);
  float m00=cell[0], m01=cell[1], m02=cell[2];
  float m10=cell[3], m11=cell[4], m12=cell[5];
  float m20=cell[6], m21=cell[7], m22=cell[8];
  float det = m00*(m11*m22 - m12*m21) - m01*(m10*m22 - m12*m20) + m02*(m10*m21 - m11*m20);
  float inv00 =  (m11*m22 - m12*m21) / det;
  float inv01 = -(m01*m22 - m02*m21) / det;
  float inv02 =  (m01*m12 - m02*m11) / det;
  float inv10 = -(m10*m22 - m12*m20) / det;
  float inv11 =  (m00*m22 - m02*m20) / det;
  float inv12 = -(m00*m12 - m02*m10) / det;
  float inv20 =  (m10*m21 - m11*m20) / det;
  float inv21 = -(m00*m21 - m01*m20) / det;
  float inv22 =  (m00*m11 - m01*m10) / det;
  const float twopi = 2.f * PI_F;
  kxx = twopi * (na*inv00 + nb*inv01 + nc*inv02);
  kyy = twopi * (na*inv10 + nb*inv11 + nc*inv12);
  kzz = twopi * (na*inv20 + nb*inv21 + nc*inv22);
  float k2 = kxx*kxx + kyy*kyy + kzz*kzz;
  const float sigma = 1.0f / 1.805132f;
  w = (4.f * PI_F / fabsf(det)) * __expf(-0.5f * sigma * sigma * k2) / k2;
}

// ---------- sfk: k-data + structure factors in one kernel.
__global__ __launch_bounds__(256)
void sfk(const float* __restrict__ pos, const float* __restrict__ q,
         const float* __restrict__ cell,
         float* __restrict__ kx, float* __restrict__ ky,
         float* __restrict__ kz, float* __restrict__ ksw,
         float* __restrict__ gc, float* __restrict__ gs) {
  __shared__ float red1[8][32], red2[8][32];
  const int kloc = threadIdx.x & 31;
  const int part = threadIdx.x >> 5;             // 0..7
  const int k = blockIdx.x * 32 + kloc;          // < KPAD2
  float kxx, kyy, kzz, w;
  kdata(k, cell, kxx, kyy, kzz, w);
  if (part == 0) { kx[k]=kxx; ky[k]=kyy; kz[k]=kzz; ksw[k]=sqrtf(w); }
  float sc = 0.f, ss = 0.f;
  const int j0 = NM + part * 384, j1 = j0 + 384;
  for (int j = j0; j < j1; ++j) {
    float kr = kxx*pos[3*j] + kyy*pos[3*j+1] + kzz*pos[3*j+2];
    float s, c;
    __sincosf(kr, &s, &c);
    float qj = q[j];
    sc += qj * c;
    ss += qj * s;
  }
  red1[part][kloc] = sc;
  red2[part][kloc] = ss;
  __syncthreads();
  if (part == 0) {
    float tc = 0.f, ts = 0.f;
    #pragma unroll
    for (int pp = 0; pp < 8; ++pp) { tc += red1[pp][kloc]; ts += red2[pp][kloc]; }
    gc[k] = w * tc;
    gs[k] = w * ts;
  }
}

// ----------------- B = -f at metal positions; also init r2 = ones
__global__ __launch_bounds__(256)
void fB(const float* __restrict__ pos,
        const float* __restrict__ kx, const float* __restrict__ ky,
        const float* __restrict__ kz,
        const float* __restrict__ gc, const float* __restrict__ gs,
        float* __restrict__ r1, float* __restrict__ r2) {
  int i = blockIdx.x;
  float px = pos[3*i], py = pos[3*i+1], pz = pos[3*i+2];
  float p = 0.f;
  for (int k = threadIdx.x; k < KPAD2; k += 256) {
    float kr = kx[k]*px + ky[k]*py + kz[k]*pz;
    float s, c;
    __sincosf(kr, &s, &c);
    p += gc[k]*c + gs[k]*s;
  }
  for (int o = 32; o > 0; o >>= 1) p += __shfl_down(p, o, 64);
  __shared__ float red[4];
  if ((threadIdx.x & 63) == 0) red[threadIdx.x >> 6] = p;
  __syncthreads();
  if (threadIdx.x == 0) {
    r1[i] = -(red[0] + red[1] + red[2] + red[3]);
    r2[i] = 1.f;
  }
}

// --------------- A = C W C^T + S W S^T, upper 128-tiles only (bi<=bj)
__global__ __launch_bounds__(256, 2)
void gemmA(const float* __restrict__ pos,
           const float* __restrict__ kx, const float* __restrict__ ky,
           const float* __restrict__ kz, const float* __restrict__ ksw,
           float* __restrict__ A) {
  __shared__ __align__(16) float Cr[KC][128];
  __shared__ __align__(16) float Sr[KC][128];
  __shared__ __align__(16) float Cc[KC][128];
  __shared__ __align__(16) float Sc[KC][128];
  const int blk = blockIdx.x;
  const int split = blk / 36;
  const int tt = blk - split * 36;
  int bi = 0, rem = tt;
  while (rem >= 8 - bi) { rem -= 8 - bi; ++bi; }
  const int bj = bi + rem;
  const int t = threadIdx.x;
  const int side = t >> 7;
  const int a = t & 127;
  const int atom = (side ? bj : bi) * 128 + a;
  const float px = pos[3*atom], py = pos[3*atom+1], pz = pos[3*atom+2];
  float (*Cp)[128] = side ? Cc : Cr;
  float (*Sp)[128] = side ? Sc : Sr;
  const int ri0 = (t >> 4) * 4;
  const int c0  = (t & 15) * 4;
  v4 acc[2][2][4];
  #pragma unroll
  for (int qi = 0; qi < 2; ++qi)
    #pragma unroll
    for (int qj = 0; qj < 2; ++qj)
      #pragma unroll
      for (int ii = 0; ii < 4; ++ii)
        acc[qi][qj][ii] = splat4(0.f);

  for (int ch = split * CHPS; ch < split * CHPS + CHPS; ++ch) {
    const int kb = ch * KC;
    #pragma unroll 4
    for (int kk = 0; kk < KC; ++kk) {
      const int gk = kb + kk;
      float kr = kx[gk]*px + ky[gk]*py + kz[gk]*pz;
      float s, c;
      __sincosf(kr, &s, &c);
      float sw = ksw[gk];
      Cp[kk][a] = c * sw;
      Sp[kk][a] = s * sw;
    }
    __syncthreads();
    #pragma unroll 2
    for (int kk = 0; kk < KC; ++kk) {
      v4 cr0 = *(const v4*)&Cr[kk][ri0];
      v4 cr1 = *(const v4*)&Cr[kk][ri0+64];
      v4 sr0 = *(const v4*)&Sr[kk][ri0];
      v4 sr1 = *(const v4*)&Sr[kk][ri0+64];
      v4 cc0 = *(const v4*)&Cc[kk][c0];
      v4 cc1 = *(const v4*)&Cc[kk][c0+64];
      v4 sc0 = *(const v4*)&Sc[kk][c0];
      v4 sc1 = *(const v4*)&Sc[kk][c0+64];
      #pragma unroll
      for (int ii = 0; ii < 4; ++ii) {
        acc[0][0][ii] += cc0 * splat4(cr0[ii]);
        acc[0][0][ii] += sc0 * splat4(sr0[ii]);
        acc[0][1][ii] += cc1 * splat4(cr0[ii]);
        acc[0][1][ii] += sc1 * splat4(sr0[ii]);
        acc[1][0][ii] += cc0 * splat4(cr1[ii]);
        acc[1][0][ii] += sc0 * splat4(sr1[ii]);
        acc[1][1][ii] += cc1 * splat4(cr1[ii]);
        acc[1][1][ii] += sc1 * splat4(sr1[ii]);
      }
    }
    __syncthreads();
  }
  #pragma unroll
  for (int qi = 0; qi < 2; ++qi)
    #pragma unroll
    for (int qj = 0; qj < 2; ++qj)
      #pragma unroll
      for (int ii = 0; ii < 4; ++ii) {
        const int row = bi*128 + qi*64 + ri0 + ii;
        const int col = bj*128 + qj*64 + c0;
        atomicAdd(&A[row*1024 + col + 0], acc[qi][qj][ii][0]);
        atomicAdd(&A[row*1024 + col + 1], acc[qi][qj][ii][1]);
        atomicAdd(&A[row*1024 + col + 2], acc[qi][qj][ii][2]);
        atomicAdd(&A[row*1024 + col + 3], acc[qi][qj][ii][3]);
      }
}

// ============ step(p): b=32 panels, fused lazy-syrk + panel ============
// 32 steps over 32x32 tiles (body cost ~ b^2, boundary ~5us; b*=sqrt(beta/f)
// ~ 21-32, so b=32 halves the chain vs b=64). Structure identical to R10.
// First-touch rule: direct iff same 128-supertile ((x>>2) equal), else read
// the upper transpose (gemmA writes upper 128-tiles only).
__global__ __launch_bounds__(256)
void step(float* __restrict__ A, const float* __restrict__ r1, const float* __restrict__ r2,
          float* __restrict__ ru1, float* __restrict__ ru2,
          float* __restrict__ y1g, float* __restrict__ y2g, int p) {
  __shared__ float D[32][33];
  __shared__ float T[32][33];
  __shared__ float y1s[32], y2s[32];
  const int t = threadIdx.x;
  const int nb = 32 - p;
  const int i0 = (t >> 4) * 2, j0 = (t & 15) * 2;   // 2x2 micro-tile

  if ((int)blockIdx.x >= nb) {
    // ---------------- syrk role (only launched for p >= 1) ----------------
    int rem = blockIdx.x - nb, a = 0;
    while (rem >= a + 1) { rem -= (a + 1); ++a; }
    const int qi = p + 1 + a, qj = p + 1 + rem;     // qi >= qj >= p+1
    for (int e = t; e < 1024; e += 256) {
      int r = e >> 5, c = e & 31;
      D[r][c] = A[(qi*32+r)*1024 + (p-1)*32 + c];   // L(qi,p-1)
      T[r][c] = A[(qj*32+r)*1024 + (p-1)*32 + c];   // L(qj,p-1)
    }
    float o[2][2];
    if (p == 1 && (qi >> 2) != (qj >> 2)) {
      // first touch of a cross-supertile lower tile: read upper transpose
      #pragma unroll
      for (int ii = 0; ii < 2; ++ii)
        #pragma unroll
        for (int jj = 0; jj < 2; ++jj)
          o[ii][jj] = A[(qj*32 + j0+jj)*1024 + qi*32 + i0+ii];
    } else {
      #pragma unroll
      for (int ii = 0; ii < 2; ++ii)
        #pragma unroll
        for (int jj = 0; jj < 2; ++jj)
          o[ii][jj] = A[(qi*32+i0+ii)*1024 + qj*32 + j0+jj];
    }
    __syncthreads();
    for (int m = 0; m < 32; ++m) {
      float a0 = D[i0+0][m], a1 = D[i0+1][m];
      float b0 = T[j0+0][m], b1 = T[j0+1][m];
      o[0][0]-=a0*b0; o[0][1]-=a0*b1;
      o[1][0]-=a1*b0; o[1][1]-=a1*b1;
    }
    #pragma unroll
    for (int ii = 0; ii < 2; ++ii)
      #pragma unroll
      for (int jj = 0; jj < 2; ++jj)
        A[(qi*32+i0+ii)*1024 + qj*32 + j0+jj] = o[ii][jj];
    return;
  }

  // ---------------- panel role: tile (q, p) ----------------
  const int b = blockIdx.x;
  const int q = p + b;
  if (p == 0) {
    for (int e = t; e < 1024; e += 256)
      D[e>>5][e&31] = A[(e>>5)*1024 + (e&31)];                      // A(0,0)
    if (b > 0) {
      if (q < 4) {
        for (int e = t; e < 1024; e += 256)
          T[e>>5][e&31] = A[(q*32+(e>>5))*1024 + (e&31)];           // direct
      } else {
        for (int e = t; e < 1024; e += 256)
          T[e&31][e>>5] = A[(e>>5)*1024 + q*32 + (e&31)];           // A(0,q)^T
      }
    }
    __syncthreads();
  } else {
    // load column p-1 L tiles
    for (int e = t; e < 1024; e += 256)
      D[e>>5][e&31] = A[(p*32+(e>>5))*1024 + (p-1)*32 + (e&31)];    // L(p,p-1)
    if (b > 0)
      for (int e = t; e < 1024; e += 256)
        T[e>>5][e&31] = A[(q*32+(e>>5))*1024 + (p-1)*32 + (e&31)];  // L(q,p-1)
    __syncthreads();
    // diag update o1 = A(p,p) - L(p,p-1) L(p,p-1)^T
    float o1[2][2];
    #pragma unroll
    for (int ii = 0; ii < 2; ++ii)
      #pragma unroll
      for (int jj = 0; jj < 2; ++jj)
        o1[ii][jj] = A[(p*32+i0+ii)*1024 + p*32 + j0+jj];
    for (int m = 0; m < 32; ++m) {
      float a0 = D[i0+0][m], a1 = D[i0+1][m];
      float b0 = D[j0+0][m], b1 = D[j0+1][m];
      o1[0][0]-=a0*b0; o1[0][1]-=a0*b1;
      o1[1][0]-=a1*b0; o1[1][1]-=a1*b1;
    }
    float o2[2][2];
    if (b > 0) {
      // own-tile update o2 = A(q,p) - L(q,p-1) L(p,p-1)^T
      if (p == 1 && (q >> 2) != 0) {
        // first touch: read A(1,q)^T
        #pragma unroll
        for (int ii = 0; ii < 2; ++ii)
          #pragma unroll
          for (int jj = 0; jj < 2; ++jj)
            o2[ii][jj] = A[(1*32 + j0+jj)*1024 + q*32 + i0+ii];
      } else {
        #pragma unroll
        for (int ii = 0; ii < 2; ++ii)
          #pragma unroll
          for (int jj = 0; jj < 2; ++jj)
            o2[ii][jj] = A[(q*32+i0+ii)*1024 + p*32 + j0+jj];
      }
      for (int m = 0; m < 32; ++m) {
        float a0 = T[i0+0][m], a1 = T[i0+1][m];
        float b0 = D[j0+0][m], b1 = D[j0+1][m];
        o2[0][0]-=a0*b0; o2[0][1]-=a0*b1;
        o2[1][0]-=a1*b0; o2[1][1]-=a1*b1;
      }
    }
    __syncthreads();   // done reading D,T as L-tiles
    #pragma unroll
    for (int ii = 0; ii < 2; ++ii)
      #pragma unroll
      for (int jj = 0; jj < 2; ++jj)
        D[i0+ii][j0+jj] = o1[ii][jj];
    if (b > 0) {
      #pragma unroll
      for (int ii = 0; ii < 2; ++ii)
        #pragma unroll
        for (int jj = 0; jj < 2; ++jj)
          T[i0+ii][j0+jj] = o2[ii][jj];
    }
    __syncthreads();
  }

  // ---- wave-register Cholesky of D (lanes 0..31; lane = row) ----
  if (t < 32) {
    float a[32];
    #pragma unroll
    for (int m = 0; m < 32; ++m) a[m] = D[t][m];
    #pragma unroll
    for (int j = 0; j < 32; ++j) {
      float dj = __shfl(a[j], j);
      float rinv = rsqrtf(dj);
      float lj = (t == j) ? dj * rinv : a[j] * rinv;
      a[j] = lj;
      #pragma unroll
      for (int m = j + 1; m < 32; ++m)
        a[m] -= lj * __shfl(lj, m);
    }
    #pragma unroll
    for (int m = 0; m < 32; ++m) D[t][m] = a[m];  // upper garbage, never read
  }
  __syncthreads();
  if (b == 0) {
    for (int e = t; e < 1024; e += 256) {
      int i = e >> 5, j = e & 31;
      if (i >= j) A[(p*32+i)*1024 + p*32 + j] = D[i][j];
    }
  } else {
    // ---- blocked-register TRSM: solve X L^T = T (lanes 0..31 = rows) ----
    if (t < 32) {
      #pragma unroll
      for (int cb = 0; cb < 2; ++cb) {
        const int cbase = cb * 16;
        float x[16];
        #pragma unroll
        for (int k = 0; k < 16; ++k) x[k] = T[t][cbase + k];
        for (int m = 0; m < cbase; ++m) {
          float tm = T[t][m];                       // own solved value
          #pragma unroll
          for (int k = 0; k < 16; ++k)
            x[k] -= tm * D[cbase + k][m];           // broadcast L read
        }
        #pragma unroll
        for (int k = 0; k < 16; ++k) {
          float xv = x[k] * (1.0f / D[cbase + k][cbase + k]);
          x[k] = xv;
          #pragma unroll
          for (int m2 = k + 1; m2 < 16; ++m2)
            x[m2] -= xv * D[cbase + m2][cbase + k];
        }
        #pragma unroll
        for (int k = 0; k < 16; ++k) T[t][cbase + k] = x[k];
      }
    }
    __syncthreads();
    for (int e = t; e < 1024; e += 256)
      A[(q*32 + (e>>5))*1024 + p*32 + (e&31)] = T[e>>5][e&31];
  }
  __syncthreads();
  // forward solve y_p = L_pp^{-1} r_p (redundant per block, lanes 0..31)
  if (t < 32) {
    float v1 = r1[p*32 + t], v2 = r2[p*32 + t];
    for (int j = 0; j < 32; ++j) {
      float invd = 1.f / D[j][j];
      float Lij = D[t][j];
      float x1 = __shfl(v1, j) * invd;
      float x2 = __shfl(v2, j) * invd;
      if (t == j)      { v1 = x1; v2 = x2; }
      else if (t > j)  { v1 -= Lij * x1; v2 -= Lij * x2; }
    }
    y1s[t] = v1; y2s[t] = v2;
    if (b == 0) { y1g[p*32 + t] = v1; y2g[p*32 + t] = v2; }
  }
  __syncthreads();
  if (b > 0 && t < 32) {
    float a1 = 0.f, a2 = 0.f;
    for (int j = 0; j < 32; ++j) {
      float lv = T[t][j];
      a1 += lv * y1s[j];
      a2 += lv * y2s[j];
    }
    ru1[q*32 + t] -= a1;
    ru2[q*32 + t] -= a2;
  }
}

// --------- backward solve (L^T x = y, 2 RHS), lambda, final output
// (element-wise L identical regardless of factor tile size -> unchanged)
__global__ __launch_bounds__(1024)
void bwd_out(const float* __restrict__ A, float* __restrict__ y1g, float* __restrict__ y2g,
             const float* __restrict__ qin, float* __restrict__ out) {
  __shared__ float D[64][65];
  __shared__ float x1s[64], x2s[64];
  __shared__ float rs1[16], rs2[16];
  const int t = threadIdx.x;
  for (int p = 15; p >= 0; --p) {
    for (int e = t; e < 4096; e += 1024)
      D[e>>6][e&63] = A[(p*64 + (e>>6))*1024 + p*64 + (e&63)];
    __syncthreads();
    if (t < 64) {
      float v1 = y1g[p*64 + t], v2 = y2g[p*64 + t];
      for (int i = 63; i >= 0; --i) {
        float invd = 1.f / D[i][i];
        float x1 = __shfl(v1, i) * invd;
        float x2 = __shfl(v2, i) * invd;
        float Lim = D[i][t];
        if (t == i)      { v1 = x1; v2 = x2; }
        else if (t < i)  { v1 -= Lim * x1; v2 -= Lim * x2; }
      }
      y1g[p*64 + t] = v1; y2g[p*64 + t] = v2;
      x1s[t] = v1; x2s[t] = v2;
    }
    __syncthreads();
    for (int rr = t; rr < p*64; rr += 1024) {
      float a1 = 0.f, a2 = 0.f;
      #pragma unroll 8
      for (int jj = 0; jj < 64; ++jj) {
        float lv = A[(p*64+jj)*1024 + rr];
        a1 += lv * x1s[jj];
        a2 += lv * x2s[jj];
      }
      y1g[rr] -= a1; y2g[rr] -= a2;
    }
    __syncthreads();
  }
  float s1 = y1g[t], s2 = y2g[t];
  for (int o = 32; o > 0; o >>= 1) { s1 += __shfl_down(s1, o, 64); s2 += __shfl_down(s2, o, 64); }
  if ((t & 63) == 0) { rs1[t >> 6] = s1; rs2[t >> 6] = s2; }
  __syncthreads();
  if (t == 0) {
    float a = 0.f, bb = 0.f;
    #pragma unroll
    for (int w = 0; w < 16; ++w) { a += rs1[w]; bb += rs2[w]; }
    rs1[0] = a / bb;
  }
  __syncthreads();
  const float lam = rs1[0];
  out[t] = y1g[t] - lam * y2g[t];
  for (int e = NM + t; e < NATOM; e += 1024) out[e] = qin[e];
}

// --------------------------------------------------------------- launch
extern "C" void kernel_launch(void* const* d_in, const int* in_sizes, int n_in,
                              void* d_out, int out_size, void* d_ws, size_t ws_size,
                              hipStream_t stream) {
  const float* pos  = (const float*)d_in[0];
  const float* q    = (const float*)d_in[1];
  const float* cell = (const float*)d_in[2];
  float* out = (float*)d_out;

  float* ws  = (float*)d_ws;
  float* A   = ws;                                   // 1,048,576 floats
  float* kx  = ws + 1048576;
  float* ky  = kx + KPAD2;
  float* kz  = ky + KPAD2;
  float* ksw = kz + KPAD2;
  float* gc  = ksw + KPAD2;                          // KPAD2
  float* gs  = gc + KPAD2;                           // KPAD2
  float* r1  = gs + KPAD2;                           // 1024
  float* r2  = r1 + 1024;                            // 1024
  float* y1g = r2 + 1024;                            // 1024
  float* y2g = y1g + 1024;                           // 1024

  sfk<<<NCH, 256, 0, stream>>>(pos, q, cell, kx, ky, kz, ksw, gc, gs);
  fB<<<NM, 256, 0, stream>>>(pos, kx, ky, kz, gc, gs, r1, r2);
  hipMemsetAsync(A, 0, 1024 * 1024 * sizeof(float), stream);
  gemmA<<<36 * KSPLIT, 256, 0, stream>>>(pos, kx, ky, kz, ksw, A);
  for (int p = 0; p < 32; ++p) {
    const int s = 31 - p;
    const int grid = (32 - p) + ((p >= 1) ? s * (s + 1) / 2 : 0);
    step<<<grid, 256, 0, stream>>>(A, r1, r2, r1, r2, y1g, y2g, p);
  }
  bwd_out<<<1, 1024, 0, stream>>>(A, y1g, y2g, q, out);
}

// Round 12
// 974.284 us; speedup vs baseline: 2.1645x; 1.2132x over previous
//
#include <hip/hip_runtime.h>
#include <math.h>

#define NATOM 4096
#define NM    1024
#define NKR   9260      // real k-vectors (21^3 - 1)
#define KSPLIT 14
#define CHPS  22        // chunks per split
#define NCH   308       // KSPLIT*CHPS
#define KC    32
#define KPAD2 9856      // NCH*KC
#define PI_F  3.14159265358979f

typedef short v8s __attribute__((ext_vector_type(8)));   // 8 bf16 (4 VGPRs)
typedef float v4f __attribute__((ext_vector_type(4)));   // 4 fp32 acc

// ---------- k-vector data computed inline (device helper) ----------
static __device__ __forceinline__ void kdata(int t, const float* __restrict__ cell,
                                             float& kxx, float& kyy, float& kzz, float& w) {
  if (t >= NKR) { kxx = 0.f; kyy = 0.f; kzz = 0.f; w = 0.f; return; }
  int u = (t < 4630) ? t : t + 1;       // skip the all-zero triple
  int a = u / 441;
  int rem = u - a * 441;
  int b = rem / 21;
  int c = rem - b * 21;
  float na = (float)(a - 10), nb = (float)(b - 10), nc = (float)(c - 10);
  float m00=cell[0], m01=cell[1], m02=cell[2];
  float m10=cell[3], m11=cell[4], m12=cell[5];
  float m20=cell[6], m21=cell[7], m22=cell[8];
  float det = m00*(m11*m22 - m12*m21) - m01*(m10*m22 - m12*m20) + m02*(m10*m21 - m11*m20);
  float inv00 =  (m11*m22 - m12*m21) / det;
  float inv01 = -(m01*m22 - m02*m21) / det;
  float inv02 =  (m01*m12 - m02*m11) / det;
  float inv10 = -(m10*m22 - m12*m20) / det;
  float inv11 =  (m00*m22 - m02*m20) / det;
  float inv12 = -(m00*m12 - m02*m10) / det;
  float inv20 =  (m10*m21 - m11*m20) / det;
  float inv21 = -(m00*m21 - m01*m20) / det;
  float inv22 =  (m00*m11 - m01*m10) / det;
  const float twopi = 2.f * PI_F;
  kxx = twopi * (na*inv00 + nb*inv01 + nc*inv02);
  kyy = twopi * (na*inv10 + nb*inv11 + nc*inv12);
  kzz = twopi * (na*inv20 + nb*inv21 + nc*inv22);
  float k2 = kxx*kxx + kyy*kyy + kzz*kzz;
  const float sigma = 1.0f / 1.805132f;
  w = (4.f * PI_F / fabsf(det)) * __expf(-0.5f * sigma * sigma * k2) / k2;
}

// ---------- sfk: k-data + structure factors in one kernel.
__global__ __launch_bounds__(256)
void sfk(const float* __restrict__ pos, const float* __restrict__ q,
         const float* __restrict__ cell,
         float* __restrict__ kx, float* __restrict__ ky,
         float* __restrict__ kz, float* __restrict__ ksw,
         float* __restrict__ gc, float* __restrict__ gs) {
  __shared__ float red1[8][32], red2[8][32];
  const int kloc = threadIdx.x & 31;
  const int part = threadIdx.x >> 5;             // 0..7
  const int k = blockIdx.x * 32 + kloc;          // < KPAD2
  float kxx, kyy, kzz, w;
  kdata(k, cell, kxx, kyy, kzz, w);
  if (part == 0) { kx[k]=kxx; ky[k]=kyy; kz[k]=kzz; ksw[k]=sqrtf(w); }
  float sc = 0.f, ss = 0.f;
  const int j0 = NM + part * 384, j1 = j0 + 384;
  for (int j = j0; j < j1; ++j) {
    float kr = kxx*pos[3*j] + kyy*pos[3*j+1] + kzz*pos[3*j+2];
    float s, c;
    __sincosf(kr, &s, &c);
    float qj = q[j];
    sc += qj * c;
    ss += qj * s;
  }
  red1[part][kloc] = sc;
  red2[part][kloc] = ss;
  __syncthreads();
  if (part == 0) {
    float tc = 0.f, ts = 0.f;
    #pragma unroll
    for (int pp = 0; pp < 8; ++pp) { tc += red1[pp][kloc]; ts += red2[pp][kloc]; }
    gc[k] = w * tc;
    gs[k] = w * ts;
  }
}

// ----------------- B = -f at metal positions; also init r2 = ones
__global__ __launch_bounds__(256)
void fB(const float* __restrict__ pos,
        const float* __restrict__ kx, const float* __restrict__ ky,
        const float* __restrict__ kz,
        const float* __restrict__ gc, const float* __restrict__ gs,
        float* __restrict__ r1, float* __restrict__ r2) {
  int i = blockIdx.x;
  float px = pos[3*i], py = pos[3*i+1], pz = pos[3*i+2];
  float p = 0.f;
  for (int k = threadIdx.x; k < KPAD2; k += 256) {
    float kr = kx[k]*px + ky[k]*py + kz[k]*pz;
    float s, c;
    __sincosf(kr, &s, &c);
    p += gc[k]*c + gs[k]*s;
  }
  for (int o = 32; o > 0; o >>= 1) p += __shfl_down(p, o, 64);
  __shared__ float red[4];
  if ((threadIdx.x & 63) == 0) red[threadIdx.x >> 6] = p;
  __syncthreads();
  if (threadIdx.x == 0) {
    r1[i] = -(red[0] + red[1] + red[2] + red[3]);
    r2[i] = 1.f;
  }
}

// --------------- A = C W C^T + S W S^T, upper 128-tiles only (bi<=bj)
// R12: MFMA 3-pass split-bf16 (hi*hi + hi*mid + mid*hi), per C and S.
// LDS planes [side*4+{Chi,Cmid,Shi,Smid}][atom][k], stride 40 shorts
// (80B rows: 16B-aligned b128 reads, 20-dword bank stride = 2-way free).
// Frag layouts (HW-verified): A[m=lane&15][k=(lane>>4)*8+j]; B symmetric;
// C/D col=lane&15, row=(lane>>4)*4+reg.
#define PSTR 40
__global__ __launch_bounds__(256, 2)
void gemmA(const float* __restrict__ pos,
           const float* __restrict__ kx, const float* __restrict__ ky,
           const float* __restrict__ kz, const float* __restrict__ ksw,
           float* __restrict__ A) {
  __shared__ short Pl[8][128 * PSTR];
  const int blk = blockIdx.x;
  const int split = blk / 36;
  const int tt = blk - split * 36;
  int bi = 0, rem = tt;
  while (rem >= 8 - bi) { rem -= 8 - bi; ++bi; }
  const int bj = bi + rem;
  const int t = threadIdx.x;
  const int side = t >> 7;
  const int a = t & 127;
  const int atom = (side ? bj : bi) * 128 + a;
  const float px = pos[3*atom], py = pos[3*atom+1], pz = pos[3*atom+2];
  short* PC_hi = &Pl[side*4+0][a*PSTR];
  short* PC_mi = &Pl[side*4+1][a*PSTR];
  short* PS_hi = &Pl[side*4+2][a*PSTR];
  short* PS_mi = &Pl[side*4+3][a*PSTR];

  const int w = t >> 6;          // wave id 0..3 -> rows [w*32, w*32+32)
  const int lane = t & 63;
  const int ln15 = lane & 15;
  const int quad = lane >> 4;

  v4f acc[2][8];
  #pragma unroll
  for (int mt = 0; mt < 2; ++mt)
    #pragma unroll
    for (int nt = 0; nt < 8; ++nt) {
      v4f z = {0.f, 0.f, 0.f, 0.f};
      acc[mt][nt] = z;
    }

  for (int ch = split * CHPS; ch < split * CHPS + CHPS; ++ch) {
    const int kb = ch * KC;
    // ---- staging: sincos -> (hi, mid) bf16 split, packed 8-k b128 writes
    #pragma unroll
    for (int g = 0; g < 4; ++g) {
      v8s vch, vcm, vsh, vsm;
      #pragma unroll
      for (int j = 0; j < 8; ++j) {
        const int gk = kb + g*8 + j;
        float kr = kx[gk]*px + ky[gk]*py + kz[gk]*pz;
        float s, c;
        __sincosf(kr, &s, &c);
        float sw = ksw[gk];
        float cv = c * sw, sv = s * sw;
        unsigned cu = __float_as_uint(cv);
        float chf = __uint_as_float(cu & 0xffff0000u);
        unsigned cmu = __float_as_uint(cv - chf);
        unsigned su = __float_as_uint(sv);
        float shf = __uint_as_float(su & 0xffff0000u);
        unsigned smu = __float_as_uint(sv - shf);
        vch[j] = (short)(cu >> 16);
        vcm[j] = (short)(cmu >> 16);
        vsh[j] = (short)(su >> 16);
        vsm[j] = (short)(smu >> 16);
      }
      *(v8s*)&PC_hi[g*8] = vch;
      *(v8s*)&PC_mi[g*8] = vcm;
      *(v8s*)&PS_hi[g*8] = vsh;
      *(v8s*)&PS_mi[g*8] = vsm;
    }
    __syncthreads();
    // ---- MFMA main: one K=32 step per chunk
    v8s aCh[2], aCm[2], aSh[2], aSm[2];
    #pragma unroll
    for (int mt = 0; mt < 2; ++mt) {
      const int off = (w*32 + mt*16 + ln15) * PSTR + quad*8;
      aCh[mt] = *(const v8s*)&Pl[0][off];
      aCm[mt] = *(const v8s*)&Pl[1][off];
      aSh[mt] = *(const v8s*)&Pl[2][off];
      aSm[mt] = *(const v8s*)&Pl[3][off];
    }
    #pragma unroll
    for (int nt = 0; nt < 8; ++nt) {
      const int off = (nt*16 + ln15) * PSTR + quad*8;
      v8s bCh = *(const v8s*)&Pl[4][off];
      v8s bCm = *(const v8s*)&Pl[5][off];
      v8s bSh = *(const v8s*)&Pl[6][off];
      v8s bSm = *(const v8s*)&Pl[7][off];
      #pragma unroll
      for (int mt = 0; mt < 2; ++mt) {
        v4f d = acc[mt][nt];
        d = __builtin_amdgcn_mfma_f32_16x16x32_bf16(aCh[mt], bCh, d, 0, 0, 0);
        d = __builtin_amdgcn_mfma_f32_16x16x32_bf16(aCh[mt], bCm, d, 0, 0, 0);
        d = __builtin_amdgcn_mfma_f32_16x16x32_bf16(aCm[mt], bCh, d, 0, 0, 0);
        d = __builtin_amdgcn_mfma_f32_16x16x32_bf16(aSh[mt], bSh, d, 0, 0, 0);
        d = __builtin_amdgcn_mfma_f32_16x16x32_bf16(aSh[mt], bSm, d, 0, 0, 0);
        d = __builtin_amdgcn_mfma_f32_16x16x32_bf16(aSm[mt], bSh, d, 0, 0, 0);
        acc[mt][nt] = d;
      }
    }
    __syncthreads();
  }
  // ---- epilogue: C/D layout col=lane&15, row=quad*4+reg; atomic accumulate
  #pragma unroll
  for (int mt = 0; mt < 2; ++mt)
    #pragma unroll
    for (int nt = 0; nt < 8; ++nt)
      #pragma unroll
      for (int r = 0; r < 4; ++r) {
        const int row = bi*128 + w*32 + mt*16 + quad*4 + r;
        const int col = bj*128 + nt*16 + ln15;
        atomicAdd(&A[row*1024 + col], acc[mt][nt][r]);
      }
}

// ============ step(p): b=32 panels, fused lazy-syrk + panel (R11 verbatim) ============
__global__ __launch_bounds__(256)
void step(float* __restrict__ A, const float* __restrict__ r1, const float* __restrict__ r2,
          float* __restrict__ ru1, float* __restrict__ ru2,
          float* __restrict__ y1g, float* __restrict__ y2g, int p) {
  __shared__ float D[32][33];
  __shared__ float T[32][33];
  __shared__ float y1s[32], y2s[32];
  const int t = threadIdx.x;
  const int nb = 32 - p;
  const int i0 = (t >> 4) * 2, j0 = (t & 15) * 2;   // 2x2 micro-tile

  if ((int)blockIdx.x >= nb) {
    // ---------------- syrk role (only launched for p >= 1) ----------------
    int rem = blockIdx.x - nb, a = 0;
    while (rem >= a + 1) { rem -= (a + 1); ++a; }
    const int qi = p + 1 + a, qj = p + 1 + rem;     // qi >= qj >= p+1
    for (int e = t; e < 1024; e += 256) {
      int r = e >> 5, c = e & 31;
      D[r][c] = A[(qi*32+r)*1024 + (p-1)*32 + c];   // L(qi,p-1)
      T[r][c] = A[(qj*32+r)*1024 + (p-1)*32 + c];   // L(qj,p-1)
    }
    float o[2][2];
    if (p == 1 && (qi >> 2) != (qj >> 2)) {
      #pragma unroll
      for (int ii = 0; ii < 2; ++ii)
        #pragma unroll
        for (int jj = 0; jj < 2; ++jj)
          o[ii][jj] = A[(qj*32 + j0+jj)*1024 + qi*32 + i0+ii];
    } else {
      #pragma unroll
      for (int ii = 0; ii < 2; ++ii)
        #pragma unroll
        for (int jj = 0; jj < 2; ++jj)
          o[ii][jj] = A[(qi*32+i0+ii)*1024 + qj*32 + j0+jj];
    }
    __syncthreads();
    for (int m = 0; m < 32; ++m) {
      float a0 = D[i0+0][m], a1 = D[i0+1][m];
      float b0 = T[j0+0][m], b1 = T[j0+1][m];
      o[0][0]-=a0*b0; o[0][1]-=a0*b1;
      o[1][0]-=a1*b0; o[1][1]-=a1*b1;
    }
    #pragma unroll
    for (int ii = 0; ii < 2; ++ii)
      #pragma unroll
      for (int jj = 0; jj < 2; ++jj)
        A[(qi*32+i0+ii)*1024 + qj*32 + j0+jj] = o[ii][jj];
    return;
  }

  // ---------------- panel role: tile (q, p) ----------------
  const int b = blockIdx.x;
  const int q = p + b;
  if (p == 0) {
    for (int e = t; e < 1024; e += 256)
      D[e>>5][e&31] = A[(e>>5)*1024 + (e&31)];                      // A(0,0)
    if (b > 0) {
      if (q < 4) {
        for (int e = t; e < 1024; e += 256)
          T[e>>5][e&31] = A[(q*32+(e>>5))*1024 + (e&31)];           // direct
      } else {
        for (int e = t; e < 1024; e += 256)
          T[e&31][e>>5] = A[(e>>5)*1024 + q*32 + (e&31)];           // A(0,q)^T
      }
    }
    __syncthreads();
  } else {
    for (int e = t; e < 1024; e += 256)
      D[e>>5][e&31] = A[(p*32+(e>>5))*1024 + (p-1)*32 + (e&31)];    // L(p,p-1)
    if (b > 0)
      for (int e = t; e < 1024; e += 256)
        T[e>>5][e&31] = A[(q*32+(e>>5))*1024 + (p-1)*32 + (e&31)];  // L(q,p-1)
    __syncthreads();
    float o1[2][2];
    #pragma unroll
    for (int ii = 0; ii < 2; ++ii)
      #pragma unroll
      for (int jj = 0; jj < 2; ++jj)
        o1[ii][jj] = A[(p*32+i0+ii)*1024 + p*32 + j0+jj];
    for (int m = 0; m < 32; ++m) {
      float a0 = D[i0+0][m], a1 = D[i0+1][m];
      float b0 = D[j0+0][m], b1 = D[j0+1][m];
      o1[0][0]-=a0*b0; o1[0][1]-=a0*b1;
      o1[1][0]-=a1*b0; o1[1][1]-=a1*b1;
    }
    float o2[2][2];
    if (b > 0) {
      if (p == 1 && (q >> 2) != 0) {
        #pragma unroll
        for (int ii = 0; ii < 2; ++ii)
          #pragma unroll
          for (int jj = 0; jj < 2; ++jj)
            o2[ii][jj] = A[(1*32 + j0+jj)*1024 + q*32 + i0+ii];
      } else {
        #pragma unroll
        for (int ii = 0; ii < 2; ++ii)
          #pragma unroll
          for (int jj = 0; jj < 2; ++jj)
            o2[ii][jj] = A[(q*32+i0+ii)*1024 + p*32 + j0+jj];
      }
      for (int m = 0; m < 32; ++m) {
        float a0 = T[i0+0][m], a1 = T[i0+1][m];
        float b0 = D[j0+0][m], b1 = D[j0+1][m];
        o2[0][0]-=a0*b0; o2[0][1]-=a0*b1;
        o2[1][0]-=a1*b0; o2[1][1]-=a1*b1;
      }
    }
    __syncthreads();   // done reading D,T as L-tiles
    #pragma unroll
    for (int ii = 0; ii < 2; ++ii)
      #pragma unroll
      for (int jj = 0; jj < 2; ++jj)
        D[i0+ii][j0+jj] = o1[ii][jj];
    if (b > 0) {
      #pragma unroll
      for (int ii = 0; ii < 2; ++ii)
        #pragma unroll
        for (int jj = 0; jj < 2; ++jj)
          T[i0+ii][j0+jj] = o2[ii][jj];
    }
    __syncthreads();
  }

  // ---- wave-register Cholesky of D (lanes 0..31; lane = row) ----
  if (t < 32) {
    float a[32];
    #pragma unroll
    for (int m = 0; m < 32; ++m) a[m] = D[t][m];
    #pragma unroll
    for (int j = 0; j < 32; ++j) {
      float dj = __shfl(a[j], j);
      float rinv = rsqrtf(dj);
      float lj = (t == j) ? dj * rinv : a[j] * rinv;
      a[j] = lj;
      #pragma unroll
      for (int m = j + 1; m < 32; ++m)
        a[m] -= lj * __shfl(lj, m);
    }
    #pragma unroll
    for (int m = 0; m < 32; ++m) D[t][m] = a[m];  // upper garbage, never read
  }
  __syncthreads();
  if (b == 0) {
    for (int e = t; e < 1024; e += 256) {
      int i = e >> 5, j = e & 31;
      if (i >= j) A[(p*32+i)*1024 + p*32 + j] = D[i][j];
    }
  } else {
    // ---- blocked-register TRSM: solve X L^T = T (lanes 0..31 = rows) ----
    if (t < 32) {
      #pragma unroll
      for (int cb = 0; cb < 2; ++cb) {
        const int cbase = cb * 16;
        float x[16];
        #pragma unroll
        for (int k = 0; k < 16; ++k) x[k] = T[t][cbase + k];
        for (int m = 0; m < cbase; ++m) {
          float tm = T[t][m];                       // own solved value
          #pragma unroll
          for (int k = 0; k < 16; ++k)
            x[k] -= tm * D[cbase + k][m];           // broadcast L read
        }
        #pragma unroll
        for (int k = 0; k < 16; ++k) {
          float xv = x[k] * (1.0f / D[cbase + k][cbase + k]);
          x[k] = xv;
          #pragma unroll
          for (int m2 = k + 1; m2 < 16; ++m2)
            x[m2] -= xv * D[cbase + m2][cbase + k];
        }
        #pragma unroll
        for (int k = 0; k < 16; ++k) T[t][cbase + k] = x[k];
      }
    }
    __syncthreads();
    for (int e = t; e < 1024; e += 256)
      A[(q*32 + (e>>5))*1024 + p*32 + (e&31)] = T[e>>5][e&31];
  }
  __syncthreads();
  // forward solve y_p = L_pp^{-1} r_p (redundant per block, lanes 0..31)
  if (t < 32) {
    float v1 = r1[p*32 + t], v2 = r2[p*32 + t];
    for (int j = 0; j < 32; ++j) {
      float invd = 1.f / D[j][j];
      float Lij = D[t][j];
      float x1 = __shfl(v1, j) * invd;
      float x2 = __shfl(v2, j) * invd;
      if (t == j)      { v1 = x1; v2 = x2; }
      else if (t > j)  { v1 -= Lij * x1; v2 -= Lij * x2; }
    }
    y1s[t] = v1; y2s[t] = v2;
    if (b == 0) { y1g[p*32 + t] = v1; y2g[p*32 + t] = v2; }
  }
  __syncthreads();
  if (b > 0 && t < 32) {
    float a1 = 0.f, a2 = 0.f;
    for (int j = 0; j < 32; ++j) {
      float lv = T[t][j];
      a1 += lv * y1s[j];
      a2 += lv * y2s[j];
    }
    ru1[q*32 + t] -= a1;
    ru2[q*32 + t] -= a2;
  }
}

// --------- backward solve (L^T x = y, 2 RHS), lambda, final output
__global__ __launch_bounds__(1024)
void bwd_out(const float* __restrict__ A, float* __restrict__ y1g, float* __restrict__ y2g,
             const float* __restrict__ qin, float* __restrict__ out) {
  __shared__ float D[64][65];
  __shared__ float x1s[64], x2s[64];
  __shared__ float rs1[16], rs2[16];
  const int t = threadIdx.x;
  for (int p = 15; p >= 0; --p) {
    for (int e = t; e < 4096; e += 1024)
      D[e>>6][e&63] = A[(p*64 + (e>>6))*1024 + p*64 + (e&63)];
    __syncthreads();
    if (t < 64) {
      float v1 = y1g[p*64 + t], v2 = y2g[p*64 + t];
      for (int i = 63; i >= 0; --i) {
        float invd = 1.f / D[i][i];
        float x1 = __shfl(v1, i) * invd;
        float x2 = __shfl(v2, i) * invd;
        float Lim = D[i][t];
        if (t == i)      { v1 = x1; v2 = x2; }
        else if (t < i)  { v1 -= Lim * x1; v2 -= Lim * x2; }
      }
      y1g[p*64 + t] = v1; y2g[p*64 + t] = v2;
      x1s[t] = v1; x2s[t] = v2;
    }
    __syncthreads();
    for (int rr = t; rr < p*64; rr += 1024) {
      float a1 = 0.f, a2 = 0.f;
      #pragma unroll 8
      for (int jj = 0; jj < 64; ++jj) {
        float lv = A[(p*64+jj)*1024 + rr];
        a1 += lv * x1s[jj];
        a2 += lv * x2s[jj];
      }
      y1g[rr] -= a1; y2g[rr] -= a2;
    }
    __syncthreads();
  }
  float s1 = y1g[t], s2 = y2g[t];
  for (int o = 32; o > 0; o >>= 1) { s1 += __shfl_down(s1, o, 64); s2 += __shfl_down(s2, o, 64); }
  if ((t & 63) == 0) { rs1[t >> 6] = s1; rs2[t >> 6] = s2; }
  __syncthreads();
  if (t == 0) {
    float a = 0.f, bb = 0.f;
    #pragma unroll
    for (int w = 0; w < 16; ++w) { a += rs1[w]; bb += rs2[w]; }
    rs1[0] = a / bb;
  }
  __syncthreads();
  const float lam = rs1[0];
  out[t] = y1g[t] - lam * y2g[t];
  for (int e = NM + t; e < NATOM; e += 1024) out[e] = qin[e];
}

// --------------------------------------------------------------- launch
extern "C" void kernel_launch(void* const* d_in, const int* in_sizes, int n_in,
                              void* d_out, int out_size, void* d_ws, size_t ws_size,
                              hipStream_t stream) {
  const float* pos  = (const float*)d_in[0];
  const float* q    = (const float*)d_in[1];
  const float* cell = (const float*)d_in[2];
  float* out = (float*)d_out;

  float* ws  = (float*)d_ws;
  float* A   = ws;                                   // 1,048,576 floats
  float* kx  = ws + 1048576;
  float* ky  = kx + KPAD2;
  float* kz  = ky + KPAD2;
  float* ksw = kz + KPAD2;
  float* gc  = ksw + KPAD2;                          // KPAD2
  float* gs  = gc + KPAD2;                           // KPAD2
  float* r1  = gs + KPAD2;                           // 1024
  float* r2  = r1 + 1024;                            // 1024
  float* y1g = r2 + 1024;                            // 1024
  float* y2g = y1g + 1024;                           // 1024

  sfk<<<NCH, 256, 0, stream>>>(pos, q, cell, kx, ky, kz, ksw, gc, gs);
  fB<<<NM, 256, 0, stream>>>(pos, kx, ky, kz, gc, gs, r1, r2);
  hipMemsetAsync(A, 0, 1024 * 1024 * sizeof(float), stream);
  gemmA<<<36 * KSPLIT, 256, 0, stream>>>(pos, kx, ky, kz, ksw, A);
  for (int p = 0; p < 32; ++p) {
    const int s = 31 - p;
    const int grid = (32 - p) + ((p >= 1) ? s * (s + 1) / 2 : 0);
    step<<<grid, 256, 0, stream>>>(A, r1, r2, r1, r2, y1g, y2g, p);
  }
  bwd_out<<<1, 1024, 0, stream>>>(A, y1g, y2g, q, out);
}